// Round 1
// baseline (244.269 us; speedup 1.0000x reference)
//
#include <hip/hip_runtime.h>

#define NB 16
#define NE 4
#define NC 4
#define NH 512
#define NW 1024
#define NPIX (NH * NW)

constexpr int THREADS = 256;
constexpr int BLOCKS_PER_BATCH = 128;
constexpr int UNITS_PER_BATCH = NPIX / 4;                                // 131072 float4 units
constexpr int ITERS = UNITS_PER_BATCH / (BLOCKS_PER_BATCH * THREADS);    // 4

// ws layout per batch (stride 36 floats):
//   [ 0..15] sums  [c*4+e]
//   [16..31] sumsq [c*4+e]
//   [32..35] counts[c]
#define WS_STRIDE 36

__global__ __launch_bounds__(THREADS) void accum_kernel(
    const float* __restrict__ pred,
    const float* __restrict__ mask,
    const int*   __restrict__ inst,
    float* __restrict__ ws)
{
    const int b   = blockIdx.y;
    const int bx  = blockIdx.x;
    const int tid = threadIdx.x;

    float s[NC][NE] = {};   // masked sums
    float q[NC][NE] = {};   // masked sum of squares
    float n[NC]     = {};   // raw pixel counts (mask-independent, per reference)

    const float4* pm = reinterpret_cast<const float4*>(mask + (size_t)b * NPIX);
    const int4*   pi = reinterpret_cast<const int4*>(inst + (size_t)b * NPIX);
    const float4* pp0 = reinterpret_cast<const float4*>(pred + ((size_t)b * NE + 0) * NPIX);
    const float4* pp1 = reinterpret_cast<const float4*>(pred + ((size_t)b * NE + 1) * NPIX);
    const float4* pp2 = reinterpret_cast<const float4*>(pred + ((size_t)b * NE + 2) * NPIX);
    const float4* pp3 = reinterpret_cast<const float4*>(pred + ((size_t)b * NE + 3) * NPIX);

    #pragma unroll
    for (int k = 0; k < ITERS; ++k) {
        const int u = bx * (THREADS * ITERS) + k * THREADS + tid;
        const float4 m4 = pm[u];
        const int4   i4 = pi[u];
        float4 p4[NE];
        p4[0] = pp0[u]; p4[1] = pp1[u]; p4[2] = pp2[u]; p4[3] = pp3[u];

        #pragma unroll
        for (int j = 0; j < 4; ++j) {
            const float mm  = (&m4.x)[j];
            const int   lab = (&i4.x)[j];
            float v[NE], sq[NE];
            #pragma unroll
            for (int e = 0; e < NE; ++e) {
                const float x = mm * (&p4[e].x)[j];
                v[e]  = x;
                sq[e] = x * x;
            }
            #pragma unroll
            for (int c = 0; c < NC; ++c) {
                const float ind = (lab == c + 1) ? 1.0f : 0.0f;
                n[c] += ind;
                #pragma unroll
                for (int e = 0; e < NE; ++e) {
                    s[c][e] = fmaf(ind, v[e],  s[c][e]);
                    q[c][e] = fmaf(ind, sq[e], q[c][e]);
                }
            }
        }
    }

    // 64-lane butterfly reduce each of the 36 accumulators
    #pragma unroll
    for (int c = 0; c < NC; ++c) {
        #pragma unroll
        for (int e = 0; e < NE; ++e) {
            #pragma unroll
            for (int off = 32; off; off >>= 1) {
                s[c][e] += __shfl_xor(s[c][e], off);
                q[c][e] += __shfl_xor(q[c][e], off);
            }
        }
        #pragma unroll
        for (int off = 32; off; off >>= 1) n[c] += __shfl_xor(n[c], off);
    }

    // block combine via LDS, then one atomicAdd per value per block
    __shared__ float red[THREADS / 64][WS_STRIDE];
    const int wave = tid >> 6;
    const int lane = tid & 63;
    if (lane == 0) {
        float* dst = red[wave];
        #pragma unroll
        for (int c = 0; c < NC; ++c)
            #pragma unroll
            for (int e = 0; e < NE; ++e) {
                dst[c * 4 + e]      = s[c][e];
                dst[16 + c * 4 + e] = q[c][e];
            }
        #pragma unroll
        for (int c = 0; c < NC; ++c) dst[32 + c] = n[c];
    }
    __syncthreads();
    if (tid < WS_STRIDE) {
        float tot = red[0][tid] + red[1][tid] + red[2][tid] + red[3][tid];
        atomicAdd(&ws[b * WS_STRIDE + tid], tot);
    }
}

__global__ __launch_bounds__(64) void finalize_kernel(
    const float* __restrict__ ws, float* __restrict__ out)
{
    const int lane = threadIdx.x;   // 0..63 -> (b, c)
    const int b = lane >> 2;
    const int c = lane & 3;
    const float* wb = ws + b * WS_STRIDE;

    const float cnt = wb[32 + c];
    float mu[NE];
    float ssd = 0.0f;
    #pragma unroll
    for (int e = 0; e < NE; ++e) {
        const float sm = wb[c * 4 + e];
        const float qq = wb[16 + c * 4 + e];
        const float m  = sm / cnt;
        mu[e] = m;
        ssd += qq - cnt * m * m;
    }
    ssd = fmaxf(ssd, 0.0f);
    const float nrm = sqrtf(ssd);
    const float dv  = nrm - 0.5f;
    float var = (nrm > 0.5f) ? dv * dv : 0.0f;

    // pairwise center repulsion; lanes are grouped 4-per-batch
    float dsum = 0.0f;
    const int base = lane & ~3;
    #pragma unroll
    for (int j = 0; j < NC; ++j) {
        float d2 = 0.0f;
        #pragma unroll
        for (int e = 0; e < NE; ++e) {
            const float mj = __shfl(mu[e], base + j);
            const float df = mu[e] - mj;
            d2 = fmaf(df, df, d2);
        }
        if (j != c) {
            const float dist = sqrtf(d2);
            const float r = fmaxf(3.0f - dist, 0.0f);
            dsum += r * r;
        }
    }

    #pragma unroll
    for (int off = 32; off; off >>= 1) {
        var  += __shfl_xor(var,  off);
        dsum += __shfl_xor(dsum, off);
    }
    if (lane == 0)
        out[0] = var / (float)(NB * NC) + dsum / (float)NB;
}

extern "C" void kernel_launch(void* const* d_in, const int* in_sizes, int n_in,
                              void* d_out, int out_size, void* d_ws, size_t ws_size,
                              hipStream_t stream) {
    const float* pred = (const float*)d_in[0];
    const float* mask = (const float*)d_in[1];
    const int*   inst = (const int*)d_in[2];
    float* out = (float*)d_out;
    float* ws  = (float*)d_ws;

    hipMemsetAsync(d_ws, 0, NB * WS_STRIDE * sizeof(float), stream);

    dim3 grid(BLOCKS_PER_BATCH, NB);
    accum_kernel<<<grid, THREADS, 0, stream>>>(pred, mask, inst, ws);
    finalize_kernel<<<1, 64, 0, stream>>>(ws, out);
}

// Round 2
// 241.054 us; speedup vs baseline: 1.0133x; 1.0133x over previous
//
#include <hip/hip_runtime.h>

#define NB 16
#define NE 4
#define NC 4
#define NPIX (512 * 1024)

constexpr int THREADS = 256;
constexpr int BPB     = 64;                       // blocks per batch
constexpr int UNITS   = NPIX / 4;                 // float4 units per batch = 131072
constexpr int ITERS   = UNITS / (BPB * THREADS);  // 8
#define WS_STRIDE 36
// ws layout: ws[(b*BPB + bx)*36 + t]; t: [0..15]=sum[c*4+e], [16..31]=sumsq, [32..35]=count[c]

__global__ __launch_bounds__(THREADS) void accum_kernel(
    const float* __restrict__ pred,
    const float* __restrict__ mask,
    const int*   __restrict__ inst,
    float* __restrict__ ws)
{
    const int b   = blockIdx.y;
    const int bx  = blockIdx.x;
    const int tid = threadIdx.x;

    float s[NC][NE] = {};
    float q[NC][NE] = {};
    float n[NC]     = {};

    const float4* pm  = reinterpret_cast<const float4*>(mask + (size_t)b * NPIX);
    const int4*   pi  = reinterpret_cast<const int4*>(inst + (size_t)b * NPIX);
    const float4* pp0 = reinterpret_cast<const float4*>(pred + ((size_t)b * NE + 0) * NPIX);
    const float4* pp1 = reinterpret_cast<const float4*>(pred + ((size_t)b * NE + 1) * NPIX);
    const float4* pp2 = reinterpret_cast<const float4*>(pred + ((size_t)b * NE + 2) * NPIX);
    const float4* pp3 = reinterpret_cast<const float4*>(pred + ((size_t)b * NE + 3) * NPIX);

    const int base = bx * (THREADS * ITERS) + tid;

    // two-deep register pipeline; all indices compile-time after full unroll
    float4 m4[2]; int4 i4[2]; float4 p[2][NE];
    {
        const int u = base;
        m4[0] = pm[u]; i4[0] = pi[u];
        p[0][0] = pp0[u]; p[0][1] = pp1[u]; p[0][2] = pp2[u]; p[0][3] = pp3[u];
    }

    #pragma unroll
    for (int k = 0; k < ITERS; ++k) {
        const int cur = k & 1, nxt = cur ^ 1;
        if (k + 1 < ITERS) {
            const int u = base + (k + 1) * THREADS;
            m4[nxt] = pm[u]; i4[nxt] = pi[u];
            p[nxt][0] = pp0[u]; p[nxt][1] = pp1[u]; p[nxt][2] = pp2[u]; p[nxt][3] = pp3[u];
        }
        #pragma unroll
        for (int j = 0; j < 4; ++j) {
            const float mm  = (&m4[cur].x)[j];
            const int   lab = (&i4[cur].x)[j];
            float v[NE], sq[NE];
            #pragma unroll
            for (int e = 0; e < NE; ++e) {
                const float x = mm * (&p[cur][e].x)[j];
                v[e]  = x;
                sq[e] = x * x;
            }
            #pragma unroll
            for (int c = 0; c < NC; ++c) {
                const float ind = (lab == c + 1) ? 1.0f : 0.0f;
                n[c] += ind;
                #pragma unroll
                for (int e = 0; e < NE; ++e) {
                    s[c][e] = fmaf(ind, v[e],  s[c][e]);
                    q[c][e] = fmaf(ind, sq[e], q[c][e]);
                }
            }
        }
    }

    // cheap tail: 2-step quad butterfly, then one LDS pass
    #pragma unroll
    for (int c = 0; c < NC; ++c) {
        #pragma unroll
        for (int e = 0; e < NE; ++e) {
            s[c][e] += __shfl_xor(s[c][e], 1); s[c][e] += __shfl_xor(s[c][e], 2);
            q[c][e] += __shfl_xor(q[c][e], 1); q[c][e] += __shfl_xor(q[c][e], 2);
        }
        n[c] += __shfl_xor(n[c], 1); n[c] += __shfl_xor(n[c], 2);
    }

    __shared__ float red[64][WS_STRIDE];   // (4 waves)*(16 quads) rows
    const int lane = tid & 63, wave = tid >> 6;
    if ((lane & 3) == 0) {
        float* dst = red[wave * 16 + (lane >> 2)];
        #pragma unroll
        for (int c = 0; c < NC; ++c) {
            #pragma unroll
            for (int e = 0; e < NE; ++e) {
                dst[c * 4 + e]      = s[c][e];
                dst[16 + c * 4 + e] = q[c][e];
            }
            dst[32 + c] = n[c];
        }
    }
    __syncthreads();

    if (tid < WS_STRIDE) {
        float tot = 0.0f;
        #pragma unroll
        for (int p2 = 0; p2 < 64; ++p2) tot += red[p2][tid];
        ws[((size_t)(b * BPB + bx)) * WS_STRIDE + tid] = tot;  // private slot: no atomics
    }
}

constexpr int FT = 640;
__global__ __launch_bounds__(FT) void finalize_kernel(
    const float* __restrict__ ws, float* __restrict__ out)
{
    __shared__ float fin[NB * WS_STRIDE];   // 576
    const int t = threadIdx.x;
    if (t < NB * WS_STRIDE) {
        const int b = t / WS_STRIDE, v = t % WS_STRIDE;
        float tot = 0.0f;
        #pragma unroll 8
        for (int blk = 0; blk < BPB; ++blk)
            tot += ws[((size_t)(b * BPB + blk)) * WS_STRIDE + v];
        fin[t] = tot;
    }
    __syncthreads();

    if (t < 64) {
        const int lane = t;
        const int b = lane >> 2;
        const int c = lane & 3;
        const float* wb = fin + b * WS_STRIDE;

        const float cnt = wb[32 + c];
        float mu[NE];
        float ssd = 0.0f;
        #pragma unroll
        for (int e = 0; e < NE; ++e) {
            const float sm = wb[c * 4 + e];
            const float qq = wb[16 + c * 4 + e];
            const float m  = sm / cnt;
            mu[e] = m;
            ssd += qq - cnt * m * m;
        }
        ssd = fmaxf(ssd, 0.0f);
        const float nrm = sqrtf(ssd);
        const float dv  = nrm - 0.5f;
        float var = (nrm > 0.5f) ? dv * dv : 0.0f;

        float dsum = 0.0f;
        const int qbase = lane & ~3;
        #pragma unroll
        for (int j = 0; j < NC; ++j) {
            float d2 = 0.0f;
            #pragma unroll
            for (int e = 0; e < NE; ++e) {
                const float mj = __shfl(mu[e], qbase + j);
                const float df = mu[e] - mj;
                d2 = fmaf(df, df, d2);
            }
            if (j != c) {
                const float dist = sqrtf(d2);
                const float r = fmaxf(3.0f - dist, 0.0f);
                dsum += r * r;
            }
        }

        #pragma unroll
        for (int off = 32; off; off >>= 1) {
            var  += __shfl_xor(var,  off);
            dsum += __shfl_xor(dsum, off);
        }
        if (lane == 0)
            out[0] = var / (float)(NB * NC) + dsum / (float)NB;
    }
}

extern "C" void kernel_launch(void* const* d_in, const int* in_sizes, int n_in,
                              void* d_out, int out_size, void* d_ws, size_t ws_size,
                              hipStream_t stream) {
    const float* pred = (const float*)d_in[0];
    const float* mask = (const float*)d_in[1];
    const int*   inst = (const int*)d_in[2];
    float* out = (float*)d_out;
    float* ws  = (float*)d_ws;

    dim3 grid(BPB, NB);
    accum_kernel<<<grid, THREADS, 0, stream>>>(pred, mask, inst, ws);
    finalize_kernel<<<1, FT, 0, stream>>>(ws, out);
}